// Round 3
// baseline (189.970 us; speedup 1.0000x reference)
//
#include <hip/hip_runtime.h>
#include <stdint.h>

typedef unsigned long long u64;

#define NNODE 4096
#define NG    8
#define M     512      // nodes per graph
#define W     8        // 64-bit words per 512-bit mask

// ---------------------------------------------------------------------------
// Single fused kernel: one block per graph (8 blocks x 1024 threads).
// Phase A: pack 512x512 0/1 diagonal block into 512-bit masks in LDS.
// Phase B: degrees + degree bit-planes.
// Phase C: sparse ego-net features (f0,f1,f2,f4,f5,f6).
// Phase D: f3 = neighbor mean of f1.
// Phase E: per-feature moments (waves 0-6) + median by rank-count (all thr).
// ---------------------------------------------------------------------------
__global__ __launch_bounds__(1024) void k_all(const float* __restrict__ A,
                                              float* __restrict__ out) {
    int g    = blockIdx.x;
    int t    = threadIdx.x;
    int wv   = t >> 6, lane = t & 63;

    __shared__ __align__(16) u64 smT[W * M];     // [w][node], 32 KB
    __shared__ int   sdegi[M];
    __shared__ u64   planes[9][W];               // degree bit-planes
    __shared__ float f1s[M];
    __shared__ __align__(16) float sfeat[7][M];  // 14 KB
    __shared__ double rsum[7][2];                // moment scratch (unused slots ok)
    __shared__ double smean[7];

    // ---- Phase A: pack. Wave wv packs rows [32*wv, 32*wv+32). Lane l covers
    // columns [8l, 8l+8) -> byte (l&7) of word (l>>3) of that row's mask.
    const float* Ab = A + ((size_t)(g * M)) * NNODE + g * M;
#pragma unroll 8
    for (int k = 0; k < 32; k++) {
        int r = wv * 32 + k;
        const float* rowp = Ab + (size_t)r * NNODE;
        float4 a = *(const float4*)(rowp + lane * 8);
        float4 b = *(const float4*)(rowp + lane * 8 + 4);
        unsigned int byte =
            (a.x != 0.f ? 1u : 0u) | (a.y != 0.f ? 2u : 0u) |
            (a.z != 0.f ? 4u : 0u) | (a.w != 0.f ? 8u : 0u) |
            (b.x != 0.f ? 16u : 0u) | (b.y != 0.f ? 32u : 0u) |
            (b.z != 0.f ? 64u : 0u) | (b.w != 0.f ? 128u : 0u);
        ((unsigned char*)smT)[((size_t)(lane >> 3) * M + r) * 8 + (lane & 7)] =
            (unsigned char)byte;
    }
    __syncthreads();

    // ---- Phase B: degrees (per node) ...
    u64 arow[W];
    int degi = 0;
    if (t < M) {
#pragma unroll
        for (int w = 0; w < W; w++) {
            arow[w] = smT[w * M + t];
            degi += __popcll(arow[w]);
        }
        sdegi[t] = degi;
    }
    __syncthreads();
    // ... and degree bit-planes (waves 0-7, wave wv = word wv).
    if (wv < W) {
        int d = sdegi[(wv << 6) + lane];
#pragma unroll
        for (int k = 0; k < 9; k++) {
            u64 bal = __ballot(((d >> k) & 1) != 0);
            if (lane == 0) planes[k][wv] = bal;
        }
    }
    __syncthreads();

    // ---- Phase C: sparse ego features (threads 0..511, node = t).
    if (t < M) {
        u64 m1[W], reach[W];
#pragma unroll
        for (int w = 0; w < W; w++) { m1[w] = arow[w]; reach[w] = 0ull; }
        m1[t >> 6] |= 1ull << (t & 63);          // M1 = A | I

        int f4 = 0;
        for (int w = 0; w < W; w++) {
            u64 bits = m1[w];
            while (bits) {                       // sparse: u in ego1(n)
                int b = __ffsll(bits) - 1;
                bits &= bits - 1;
                int u = (w << 6) + b;
#pragma unroll
                for (int w2 = 0; w2 < W; w2++) {
                    u64 r = smT[w2 * M + u];
                    reach[w2] |= r;              // B>0 mask (A symmetric)
                    f4 += __popcll(r & m1[w2]);  // edges ego1 -> ego1
                }
            }
        }
        int f6c = 0;
        u64 m2m[W];
#pragma unroll
        for (int w = 0; w < W; w++) { m2m[w] = m1[w] | reach[w]; f6c += __popcll(m2m[w]); }
        int f5i = 0, f2i = 0;
#pragma unroll
        for (int k = 0; k < 9; k++) {
            int c5 = 0, c2 = 0;
#pragma unroll
            for (int w = 0; w < W; w++) {
                c5 += __popcll(m2m[w] & planes[k][w]);   // M2 @ deg, bit-sliced
                c2 += __popcll(arow[w] & planes[k][w]);  // A  @ deg, bit-sliced
            }
            f5i += c5 << k;
            f2i += c2 << k;
        }
        float deg = (float)degi;
        float f4raw = (float)f4;
        float f1 = (deg > 1.f) ? 2.f * (f4raw - deg) / (deg * (deg - 1.f)) : 0.f;
        sfeat[0][t] = deg;
        sfeat[1][t] = f1;
        sfeat[2][t] = (deg > 0.f) ? (float)f2i / deg : 0.f;
        sfeat[4][t] = f4raw * 0.5f;
        sfeat[5][t] = (float)f5i - 2.f * f4raw;
        sfeat[6][t] = (float)f6c - deg - 1.f;
        f1s[t] = f1;
    }
    __syncthreads();

    // ---- Phase D: f3 = neighbor mean of f1 (sparse bit iteration).
    if (t < M) {
        float sum = 0.f;
#pragma unroll
        for (int w = 0; w < W; w++) {
            u64 bits = arow[w];                  // A row (no self bit)
            while (bits) {
                int b = __ffsll(bits) - 1;
                bits &= bits - 1;
                sum += f1s[(w << 6) + b];
            }
        }
        sfeat[3][t] = (degi > 0) ? sum / (float)degi : 0.f;
    }
    __syncthreads();

    // ---- Phase E1: moments. Wave f (0..6) reduces feature f across 512.
    if (wv < 7) {
        int f = wv;
        float vals[8];
        double s = 0.0;
#pragma unroll
        for (int k = 0; k < 8; k++) { vals[k] = sfeat[f][lane + 64 * k]; s += (double)vals[k]; }
#pragma unroll
        for (int off = 32; off; off >>= 1) s += __shfl_xor(s, off, 64);
        double mean = s * (1.0 / 512.0);
        double c2 = 0.0, c3 = 0.0, c4 = 0.0;
#pragma unroll
        for (int k = 0; k < 8; k++) {
            double c = (double)vals[k] - mean;
            double cc = c * c;
            c2 += cc; c3 += cc * c; c4 += cc * cc;
        }
#pragma unroll
        for (int off = 32; off; off >>= 1) {
            c2 += __shfl_xor(c2, off, 64);
            c3 += __shfl_xor(c3, off, 64);
            c4 += __shfl_xor(c4, off, 64);
        }
        if (lane == 0) {
            double m2 = c2 * (1.0 / 512.0);
            double m3 = c3 * (1.0 / 512.0);
            double m4 = c4 * (1.0 / 512.0);
            double sd = sqrt(m2);
            double den3 = m2 * sd;  if (den3 < 1e-4) den3 = 1e-4;
            double den4 = m2 * m2;  if (den4 < 1e-4) den4 = 1e-4;
            out[g * 35 + f]      = (float)mean;
            out[g * 35 + 14 + f] = (float)sd;
            out[g * 35 + 21 + f] = (float)(m3 / den3);
            out[g * 35 + 28 + f] = (float)(m4 / den4);
        }
        (void)rsum; (void)smean;
    }

    // ---- Phase E2: median, rank-count (lower-middle = rank 255).
    for (int T = t; T < 7 * M; T += 1024) {
        int f = T >> 9, i = T & (M - 1);
        float cv = sfeat[f][i];
        int less = 0, eq = 0;
        for (int j = 0; j < M; j += 4) {
            float4 x = *(const float4*)&sfeat[f][j];   // wave-uniform => broadcast
            less += (x.x < cv) + (x.y < cv) + (x.z < cv) + (x.w < cv);
            eq   += (x.x == cv) + (x.y == cv) + (x.z == cv) + (x.w == cv);
        }
        if (less <= 255 && less + eq > 255) out[g * 35 + 7 + f] = cv;
    }
}

extern "C" void kernel_launch(void* const* d_in, const int* in_sizes, int n_in,
                              void* d_out, int out_size, void* d_ws, size_t ws_size,
                              hipStream_t stream) {
    const float* A = (const float*)d_in[0];   // [4096,4096] fp32, block-diagonal 0/1
    float* out = (float*)d_out;               // [8,35] fp32
    k_all<<<NG, 1024, 0, stream>>>(A, out);
}

// Round 4
// 114.152 us; speedup vs baseline: 1.6642x; 1.6642x over previous
//
#include <hip/hip_runtime.h>
#include <stdint.h>

typedef unsigned long long u64;

#define NNODE 4096
#define NG    8
#define M     512      // nodes per graph
#define W     8        // 64-bit words per 512-bit mask

// workspace layout (bytes)
#define OFF_MASK 0                         // u64[4096][8]     = 262144 B
#define OFF_DEG  (262144)                  // float[4096]      =  16384 B
#define OFF_F1   (262144 + 16384)          // float[4096]      =  16384 B
#define OFF_FEAT (262144 + 32768)          // float[8][7][512] = 114688 B

// ---------------------------------------------------------------------------
// Kernel 1: pack diagonal-block adjacency rows into 512-bit masks + degrees.
// One wave per row; lane l covers columns [8l, 8l+8) of the block.
// ---------------------------------------------------------------------------
__global__ __launch_bounds__(256) void k_pack(const float* __restrict__ A,
                                              u64* __restrict__ gmask,
                                              float* __restrict__ gdeg) {
    int row  = (blockIdx.x << 2) + (threadIdx.x >> 6);  // 0..4095
    int lane = threadIdx.x & 63;
    int lo   = (row >> 9) << 9;                         // block column base
    const float* rowp = A + (size_t)row * NNODE + lo;
    float4 a = *(const float4*)(rowp + lane * 8);
    float4 b = *(const float4*)(rowp + lane * 8 + 4);
    unsigned int byte =
        (a.x != 0.f ? 1u : 0u) | (a.y != 0.f ? 2u : 0u) |
        (a.z != 0.f ? 4u : 0u) | (a.w != 0.f ? 8u : 0u) |
        (b.x != 0.f ? 16u : 0u) | (b.y != 0.f ? 32u : 0u) |
        (b.z != 0.f ? 64u : 0u) | (b.w != 0.f ? 128u : 0u);
    ((unsigned char*)gmask)[(size_t)row * 64 + lane] = (unsigned char)byte;
    int c = __popc(byte);
#pragma unroll
    for (int off = 32; off; off >>= 1) c += __shfl_down(c, off, 64);
    if (lane == 0) gdeg[row] = (float)c;
}

static __device__ __forceinline__ u64 shfl_xor_u64(u64 v, int mask) {
    return ((u64)(unsigned)__shfl_xor((int)(v >> 32), mask, 64) << 32) |
           (u64)(unsigned)__shfl_xor((int)(v & 0xffffffffu), mask, 64);
}

// ---------------------------------------------------------------------------
// Kernel 2: sparse ego-net features. Block = (graph, 64-node chunk) -> 64
// blocks. 4 threads per node; thread q scans m1 words {2q,2q+1} for ego
// members, partial f4/reach reduced via shfl within lane-quads.
// f5 (M2@deg) and f2 (A@deg) via degree bit-planes + popcount.
// ---------------------------------------------------------------------------
__global__ __launch_bounds__(256) void k_feat(const u64* __restrict__ gmask,
                                              const float* __restrict__ gdeg,
                                              float* __restrict__ featg,
                                              float* __restrict__ f1g) {
    int g = blockIdx.x >> 3, chunk = blockIdx.x & 7;
    int t = threadIdx.x;
    __shared__ u64 smT[W * M];      // transposed [w][node], 32 KB
    __shared__ float sdeg[M];
    __shared__ u64 planes[9][W];    // degree bit-planes

    const u64* gm = gmask + (size_t)g * M * W;
    for (int idx = t; idx < M * W; idx += 256) {
        int u = idx >> 3, w = idx & 7;
        smT[w * M + u] = gm[idx];               // coalesced global read
    }
    for (int i = t; i < M; i += 256) sdeg[i] = gdeg[g * M + i];
    __syncthreads();

    int wv = t >> 6, lane = t & 63;
    for (int w = wv; w < W; w += 4) {           // wave wv builds words wv, wv+4
        int d = (int)sdeg[(w << 6) + lane];
#pragma unroll
        for (int k = 0; k < 9; k++) {
            u64 bal = __ballot(((d >> k) & 1) != 0);
            if (lane == 0) planes[k][w] = bal;
        }
    }
    __syncthreads();

    int nl = t >> 2, q = t & 3;                 // node-in-chunk, word-pair id
    int n  = chunk * 64 + nl;
    u64 m1[W], reach[W];
#pragma unroll
    for (int w = 0; w < W; w++) { m1[w] = smT[w * M + n]; reach[w] = 0ull; }
    m1[n >> 6] |= 1ull << (n & 63);             // M1 = A | I

    int f4 = 0;
#pragma unroll
    for (int wq = 0; wq < 2; wq++) {
        int w = 2 * q + wq;
        u64 bits = m1[w];
        while (bits) {                           // sparse: u in ego1(n)
            int b = __ffsll(bits) - 1;
            bits &= bits - 1;
            int u = (w << 6) + b;
#pragma unroll
            for (int w2 = 0; w2 < W; w2++) {
                u64 r = smT[w2 * M + u];
                reach[w2] |= r;                  // B>0 mask (A symmetric)
                f4 += __popcll(r & m1[w2]);      // edges ego1 -> ego1
            }
        }
    }
    // reduce partials across the 4 q-threads of this node (same wave)
    f4 += __shfl_xor(f4, 1, 64);
    f4 += __shfl_xor(f4, 2, 64);
#pragma unroll
    for (int w = 0; w < W; w++) {
        reach[w] |= shfl_xor_u64(reach[w], 1);
        reach[w] |= shfl_xor_u64(reach[w], 2);
    }

    if (q == 0) {
        int f6c = 0;
        u64 m2m[W];
#pragma unroll
        for (int w = 0; w < W; w++) { m2m[w] = m1[w] | reach[w]; f6c += __popcll(m2m[w]); }
        int f5i = 0, f2i = 0;
        u64 arow_self = 1ull << (n & 63);        // to strip the self bit of m1
#pragma unroll
        for (int k = 0; k < 9; k++) {
            int c5 = 0, c2 = 0;
#pragma unroll
            for (int w = 0; w < W; w++) {
                u64 ar = (w == (n >> 6)) ? (m1[w] & ~arow_self) : m1[w];  // A row
                c5 += __popcll(m2m[w] & planes[k][w]);   // M2 @ deg, bit-sliced
                c2 += __popcll(ar & planes[k][w]);       // A  @ deg, bit-sliced
            }
            f5i += c5 << k;
            f2i += c2 << k;
        }
        float deg = sdeg[n];
        float f4raw = (float)f4;
        float f1 = (deg > 1.f) ? 2.f * (f4raw - deg) / (deg * (deg - 1.f)) : 0.f;
        float* fb = featg + (size_t)g * 7 * M;
        fb[0 * M + n] = deg;
        fb[1 * M + n] = f1;
        fb[2 * M + n] = (deg > 0.f) ? (float)f2i / deg : 0.f;
        fb[4 * M + n] = f4raw * 0.5f;
        fb[5 * M + n] = (float)f5i - 2.f * f4raw;
        fb[6 * M + n] = (float)f6c - deg - 1.f;
        f1g[g * M + n] = f1;
    }
}

// ---------------------------------------------------------------------------
// Kernel 3: f3 = neighbor-mean of f1. Block per graph, thread per node.
// ---------------------------------------------------------------------------
__global__ __launch_bounds__(512) void k_f3(const u64* __restrict__ gmask,
                                            const float* __restrict__ gdeg,
                                            const float* __restrict__ f1g,
                                            float* __restrict__ featg) {
    int g = blockIdx.x;
    int t = threadIdx.x;
    __shared__ float f1s[M];
    f1s[t] = f1g[g * M + t];
    __syncthreads();

    const u64* m = gmask + ((size_t)g * M + t) * W;   // row-major, 64B/thread
    float sum = 0.f;
#pragma unroll
    for (int w = 0; w < W; w++) {
        u64 bits = m[w];                               // A row (no self bit)
        while (bits) {
            int b = __ffsll(bits) - 1;
            bits &= bits - 1;
            sum += f1s[(w << 6) + b];
        }
    }
    float deg = gdeg[g * M + t];
    featg[(size_t)g * 7 * M + 3 * M + t] = (deg > 0.f) ? sum / deg : 0.f;
}

// ---------------------------------------------------------------------------
// Kernel 4: per-(graph,feature) statistics. Block = (g, f, candidate-half).
// Median by rank-count with float4 LDS broadcast; moments in double (half 0).
// ---------------------------------------------------------------------------
__global__ __launch_bounds__(256) void k_stats(const float* __restrict__ featg,
                                               float* __restrict__ out) {
    int blk = blockIdx.x;            // 0..111
    int gf = blk >> 1, half = blk & 1;
    int g = gf / 7, f = gf % 7;
    int t = threadIdx.x;
    __shared__ __align__(16) float sv[M];
    __shared__ double rsum[4], r2[4], r3[4], r4[4];
    __shared__ double smean;

    sv[t]       = featg[(size_t)gf * M + t];
    sv[t + 256] = featg[(size_t)gf * M + t + 256];
    __syncthreads();

    int wv = t >> 6, lane = t & 63;
    if (half == 0) {                 // moments only once per (g,f)
        double s = (double)sv[t] + (double)sv[t + 256];
#pragma unroll
        for (int off = 32; off; off >>= 1) s += __shfl_xor(s, off, 64);
        if (lane == 0) rsum[wv] = s;
        __syncthreads();
        if (t == 0) smean = (rsum[0] + rsum[1] + rsum[2] + rsum[3]) * (1.0 / 512.0);
        __syncthreads();
        double mean = smean;
        double c1 = (double)sv[t] - mean, c2v = (double)sv[t + 256] - mean;
        double a2 = c1 * c1, b2 = c2v * c2v;
        double p2 = a2 + b2, p3 = a2 * c1 + b2 * c2v, p4 = a2 * a2 + b2 * b2;
#pragma unroll
        for (int off = 32; off; off >>= 1) {
            p2 += __shfl_xor(p2, off, 64);
            p3 += __shfl_xor(p3, off, 64);
            p4 += __shfl_xor(p4, off, 64);
        }
        if (lane == 0) { r2[wv] = p2; r3[wv] = p3; r4[wv] = p4; }
        __syncthreads();
        if (t == 0) {
            double m2 = (r2[0] + r2[1] + r2[2] + r2[3]) * (1.0 / 512.0);
            double m3 = (r3[0] + r3[1] + r3[2] + r3[3]) * (1.0 / 512.0);
            double m4 = (r4[0] + r4[1] + r4[2] + r4[3]) * (1.0 / 512.0);
            double sd = sqrt(m2);
            double den3 = m2 * sd;  if (den3 < 1e-4) den3 = 1e-4;
            double den4 = m2 * m2;  if (den4 < 1e-4) den4 = 1e-4;
            out[g * 35 + f]      = (float)smean;
            out[g * 35 + 14 + f] = (float)sd;
            out[g * 35 + 21 + f] = (float)(m3 / den3);
            out[g * 35 + 28 + f] = (float)(m4 / den4);
        }
    }

    // median: lower-middle element = rank 255 (torch.median semantics)
    float cv = sv[half * 256 + t];
    int less = 0, eq = 0;
    for (int j = 0; j < M; j += 4) {
        float4 x = *(const float4*)&sv[j];       // wave-uniform => broadcast
        less += (x.x < cv) + (x.y < cv) + (x.z < cv) + (x.w < cv);
        eq   += (x.x == cv) + (x.y == cv) + (x.z == cv) + (x.w == cv);
    }
    if (less <= 255 && less + eq > 255) out[g * 35 + 7 + f] = cv;
}

extern "C" void kernel_launch(void* const* d_in, const int* in_sizes, int n_in,
                              void* d_out, int out_size, void* d_ws, size_t ws_size,
                              hipStream_t stream) {
    const float* A = (const float*)d_in[0];   // [4096,4096] fp32, block-diagonal 0/1
    float* out = (float*)d_out;               // [8,35] fp32
    char* ws = (char*)d_ws;
    u64*   gmask = (u64*)(ws + OFF_MASK);
    float* gdeg  = (float*)(ws + OFF_DEG);
    float* f1g   = (float*)(ws + OFF_F1);
    float* featg = (float*)(ws + OFF_FEAT);

    k_pack <<<NNODE / 4, 256, 0, stream>>>(A, gmask, gdeg);
    k_feat <<<NG * 8,    256, 0, stream>>>(gmask, gdeg, featg, f1g);
    k_f3   <<<NG,        512, 0, stream>>>(gmask, gdeg, f1g, featg);
    k_stats<<<NG * 7 * 2, 256, 0, stream>>>(featg, out);
}